// Round 4
// baseline (738.370 us; speedup 1.0000x reference)
//
#include <hip/hip_runtime.h>
#include <hip/hip_cooperative_groups.h>
#include <math.h>

namespace cg = cooperative_groups;

#define F_NODES 16384
#define DEG 8
#define E_TOT (F_NODES * DEG)   // 131072
#define B 64
#define H 16
#define LAYERS 10

#define NB  256                 // blocks (1 per CU)
#define TPB 1024                // 16 waves
#define NPB (F_NODES / NB)      // 64 nodes per block
#define NPW (NPB / (TPB / 64))  // 4 nodes per wave

// ---------------------------------------------------------------------------
// Transpose x0 (B, E) -> x0T (E, B). Tiled through LDS, both sides coalesced.
// ---------------------------------------------------------------------------
__global__ __launch_bounds__(256) void transpose_in_kernel(
    const float* __restrict__ x0, float* __restrict__ xT)
{
    __shared__ float tile[64 * 65];
    const int e0 = blockIdx.x * 64;
    const int c  = threadIdx.x & 63;
    const int r  = threadIdx.x >> 6;

    #pragma unroll
    for (int i = 0; i < 16; ++i) {
        const int b = r + i * 4;
        tile[c * 65 + b] = x0[(size_t)b * E_TOT + e0 + c];
    }
    __syncthreads();
    const int b = threadIdx.x & 63;
    #pragma unroll
    for (int i = 0; i < 16; ++i) {
        const int el = r + i * 4;
        xT[(size_t)(e0 + el) * B + b] = tile[el * 65 + b];
    }
}

// inv[P[k]] = k  (P = flat in_ixs, a permutation of E)
__global__ __launch_bounds__(256) void build_inv_kernel(
    const int* __restrict__ in_ixs, int* __restrict__ inv)
{
    const int k = blockIdx.x * 256 + threadIdx.x;
    inv[in_ixs[k]] = k;
}

__device__ __forceinline__ float fast_elu(float x)
{
    float e = __builtin_amdgcn_exp2f(x * 1.44269504088896340736f) - 1.0f;
    return x > 0.0f ? x : e;
}

// ---------------------------------------------------------------------------
// Fused persistent GSNN: all 10 layers in one cooperative launch.
// Block b owns nodes [b*64, b*64+64); wave owns 4 nodes for the whole run.
//  - residual x0T for the wave's nodes lives in registers (loaded once)
//  - weights for a block's nodes are re-read each layer -> L2-resident
//  - inter-layer activations z are PRE-PERMUTED (z[k] = x[P[k]]): reads are
//    sequential, the permutation is applied by scatter-stores via inv
//  - grid.sync() between layers
// ---------------------------------------------------------------------------
__global__ __launch_bounds__(TPB, 4) void gsnn_fused(
    const float* __restrict__ x0T,    // (E, B)
    const float* __restrict__ W1,     // (F, H, DEG)
    const float* __restrict__ b1,     // (F, H)
    const float* __restrict__ W2,     // (F, DEG, H)
    const float* __restrict__ b2,     // (F, DEG)
    const int*   __restrict__ in_ixs, // (F, DEG) = P
    const int*   __restrict__ inv,    // (E)      = P^-1
    float* __restrict__ zA,           // ping
    float* __restrict__ zB,           // pong
    float* __restrict__ out)          // (B, E) final
{
    cg::grid_group grid = cg::this_grid();

    const int lane = threadIdx.x & 63;
    const int wv   = threadIdx.x >> 6;                       // 0..15
    const int f0   = __builtin_amdgcn_readfirstlane(
                        (int)blockIdx.x * NPB + wv * NPW);   // first node

    // residual for this wave's 4 nodes: 32 VGPRs, loaded once
    float r[NPW][DEG];
    {
        const float* rp = x0T + (size_t)f0 * DEG * B + lane;
        #pragma unroll
        for (int n = 0; n < NPW; ++n)
            #pragma unroll
            for (int d = 0; d < DEG; ++d)
                r[n][d] = rp[(n * DEG + d) * B];
    }

    const float* zin  = nullptr;
    float*       zout = zA;

    for (int l = 0; l < LAYERS; ++l) {
        // ---- input: 32 loads issued up front ----
        float g[NPW][DEG];
        if (l == 0) {
            // gather x0T[P[e]] (random 256B reads)
            #pragma unroll
            for (int n = 0; n < NPW; ++n) {
                const int* ixp = in_ixs + (f0 + n) * DEG;   // s_load
                #pragma unroll
                for (int d = 0; d < DEG; ++d)
                    g[n][d] = x0T[(size_t)ixp[d] * B + lane];
            }
        } else {
            const float* zp = zin + (size_t)f0 * DEG * B + lane;
            #pragma unroll
            for (int n = 0; n < NPW; ++n)
                #pragma unroll
                for (int d = 0; d < DEG; ++d)
                    g[n][d] = zp[(n * DEG + d) * B];
        }

        // ---- per-node MLP + residual ----
        #pragma unroll
        for (int n = 0; n < NPW; ++n) {
            const int f = f0 + n;
            const float* w1  = W1 + f * (H * DEG);
            const float* bb1 = b1 + f * H;
            float h[H];
            #pragma unroll
            for (int j = 0; j < H; ++j) {
                float acc = bb1[j];
                #pragma unroll
                for (int d = 0; d < DEG; ++d)
                    acc = fmaf(w1[j * DEG + d], g[n][d], acc);
                h[j] = fast_elu(acc);
            }

            const float* w2  = W2 + f * (DEG * H);
            const float* bb2 = b2 + f * DEG;
            float o[DEG];
            #pragma unroll
            for (int d = 0; d < DEG; ++d) {
                float acc = bb2[d];
                #pragma unroll
                for (int j = 0; j < H; ++j)
                    acc = fmaf(w2[d * H + j], h[j], acc);
                o[d] = acc + r[n][d];
            }

            if (l == LAYERS - 1) {
                // final: natural (B, E); lane b owns 8 consecutive floats
                float4 v0 = make_float4(o[0], o[1], o[2], o[3]);
                float4 v1 = make_float4(o[4], o[5], o[6], o[7]);
                float4* dst = (float4*)(out + (size_t)lane * E_TOT + f * DEG);
                dst[0] = v0;
                dst[1] = v1;
            } else {
                // scatter into pre-permuted layout for next layer's seq read
                const int* invp = inv + f * DEG;            // s_load
                #pragma unroll
                for (int d = 0; d < DEG; ++d)
                    zout[(size_t)invp[d] * B + lane] = o[d];
            }
        }

        if (l < LAYERS - 1) {
            grid.sync();
            zin  = zout;
            zout = (zout == zA) ? zB : zA;
        }
    }
}

extern "C" void kernel_launch(void* const* d_in, const int* in_sizes, int n_in,
                              void* d_out, int out_size, void* d_ws, size_t ws_size,
                              hipStream_t stream)
{
    const float* x0     = (const float*)d_in[0];
    const float* W1     = (const float*)d_in[1];
    const float* b1     = (const float*)d_in[2];
    const float* W2     = (const float*)d_in[3];
    const float* b2     = (const float*)d_in[4];
    const int*   in_ixs = (const int*)d_in[5];
    float* out = (float*)d_out;

    const size_t NEL = (size_t)E_TOT * B;   // 8.39M floats = 32 MB
    float* buf0 = (float*)d_ws;             // x0T
    float* bufA = buf0 + NEL;
    float* bufB = bufA + NEL;
    int*   inv  = (int*)(bufB + NEL);       // 512 KB

    transpose_in_kernel<<<E_TOT / 64, 256, 0, stream>>>(x0, buf0);
    build_inv_kernel<<<E_TOT / 256, 256, 0, stream>>>(in_ixs, inv);

    void* args[] = {
        (void*)&buf0, (void*)&W1, (void*)&b1, (void*)&W2, (void*)&b2,
        (void*)&in_ixs, (void*)&inv, (void*)&bufA, (void*)&bufB, (void*)&out
    };
    hipLaunchCooperativeKernel((const void*)gsnn_fused,
                               dim3(NB), dim3(TPB), args, 0, stream);
}

// Round 5
// 389.448 us; speedup vs baseline: 1.8959x; 1.8959x over previous
//
#include <hip/hip_runtime.h>
#include <math.h>

#define F_NODES 16384
#define DEG 8
#define E_TOT (F_NODES * DEG)   // 131072
#define B 64
#define H 16
#define LAYERS 10

#define WPB 8                   // waves per block
#define TPB (WPB * 64)          // 512 threads
#define NPW 4                   // nodes per wave
#define NODES_PER_BLOCK (WPB * NPW)          // 32
#define GRID (F_NODES / NODES_PER_BLOCK)     // 512 blocks -> 4096 waves = 16/CU

// ---------------------------------------------------------------------------
// Transpose x0 (B, E) -> x0T (E, B). Tiled through LDS, both sides coalesced.
// ---------------------------------------------------------------------------
__global__ __launch_bounds__(256) void transpose_in_kernel(
    const float* __restrict__ x0, float* __restrict__ xT)
{
    __shared__ float tile[64 * 65];
    const int e0 = blockIdx.x * 64;
    const int c  = threadIdx.x & 63;
    const int r  = threadIdx.x >> 6;

    #pragma unroll
    for (int i = 0; i < 16; ++i) {
        const int b = r + i * 4;
        tile[c * 65 + b] = x0[(size_t)b * E_TOT + e0 + c];
    }
    __syncthreads();
    const int b = threadIdx.x & 63;
    #pragma unroll
    for (int i = 0; i < 16; ++i) {
        const int el = r + i * 4;
        xT[(size_t)(e0 + el) * B + b] = tile[el * 65 + b];
    }
}

__device__ __forceinline__ float fast_elu(float x)
{
    float e = __builtin_amdgcn_exp2f(x * 1.44269504088896340736f) - 1.0f;
    return x > 0.0f ? x : e;
}

// ---------------------------------------------------------------------------
// One GSNN layer, natural (E, B) activation layout. Wave owns NPW=4 nodes.
// lane = batch b. All 64 use-once loads (32 gathers + 32 residual) are issued
// up-front per wave for max memory-level parallelism; z traffic (read-once /
// write-once per dispatch) uses nontemporal ops so it does not write-allocate
// and thrash the 4MB/XCD L2 (keeps weights + x0T cache-resident instead).
// Weights/biases/indices are wave-uniform -> s_load.
// ---------------------------------------------------------------------------
template <bool FINAL>
__global__ __launch_bounds__(TPB, 4) void layer_kernel(
    const float* __restrict__ xin,    // (E, B) natural, previous activations
    const float* __restrict__ x0T,    // (E, B) residual source
    const float* __restrict__ W1,     // (F, H, DEG)
    const float* __restrict__ b1,     // (F, H)
    const float* __restrict__ W2,     // (F, DEG, H)
    const float* __restrict__ b2,     // (F, DEG)
    const int*   __restrict__ in_ixs, // (F, DEG)
    float* __restrict__ xout)         // (E, B) natural, or (B, E) if FINAL
{
    const int lane = threadIdx.x & 63;
    const int wv   = threadIdx.x >> 6;                     // 0..WPB-1
    const int f0   = __builtin_amdgcn_readfirstlane(
                        ((int)blockIdx.x * WPB + wv) * NPW);

    // ---- issue all 64 independent loads up-front ----
    float g[NPW][DEG];   // gathered inputs  (random 256B granules)
    float r[NPW][DEG];   // residual         (sequential)
    #pragma unroll
    for (int n = 0; n < NPW; ++n) {
        const int* ixp = in_ixs + (f0 + n) * DEG;          // s_load
        #pragma unroll
        for (int d = 0; d < DEG; ++d)
            g[n][d] = __builtin_nontemporal_load(
                          xin + (size_t)ixp[d] * B + lane);
    }
    #pragma unroll
    for (int n = 0; n < NPW; ++n) {
        const float* rp = x0T + (size_t)(f0 + n) * DEG * B + lane;
        #pragma unroll
        for (int d = 0; d < DEG; ++d)
            r[n][d] = __builtin_nontemporal_load(rp + d * B);
    }

    // ---- per-node MLP + residual ----
    #pragma unroll
    for (int n = 0; n < NPW; ++n) {
        const int f = f0 + n;
        const float* w1  = W1 + f * (H * DEG);
        const float* bb1 = b1 + f * H;
        float h[H];
        #pragma unroll
        for (int j = 0; j < H; ++j) {
            float acc = bb1[j];
            #pragma unroll
            for (int d = 0; d < DEG; ++d)
                acc = fmaf(w1[j * DEG + d], g[n][d], acc);
            h[j] = fast_elu(acc);
        }

        const float* w2  = W2 + f * (DEG * H);
        const float* bb2 = b2 + f * DEG;
        float o[DEG];
        #pragma unroll
        for (int d = 0; d < DEG; ++d) {
            float acc = bb2[d];
            #pragma unroll
            for (int j = 0; j < H; ++j)
                acc = fmaf(w2[d * H + j], h[j], acc);
            o[d] = acc + r[n][d];
        }

        if (FINAL) {
            // natural (B, E) output: lane b owns 8 consecutive floats
            float4 v0 = make_float4(o[0], o[1], o[2], o[3]);
            float4 v1 = make_float4(o[4], o[5], o[6], o[7]);
            float4* dst = (float4*)(xout + (size_t)lane * E_TOT + f * DEG);
            dst[0] = v0;
            dst[1] = v1;
        } else {
            float* outp = xout + (size_t)f * DEG * B + lane;
            #pragma unroll
            for (int d = 0; d < DEG; ++d)
                __builtin_nontemporal_store(o[d], outp + d * B);
        }
    }
}

extern "C" void kernel_launch(void* const* d_in, const int* in_sizes, int n_in,
                              void* d_out, int out_size, void* d_ws, size_t ws_size,
                              hipStream_t stream)
{
    const float* x0     = (const float*)d_in[0];
    const float* W1     = (const float*)d_in[1];
    const float* b1     = (const float*)d_in[2];
    const float* W2     = (const float*)d_in[3];
    const float* b2     = (const float*)d_in[4];
    const int*   in_ixs = (const int*)d_in[5];
    float* out = (float*)d_out;

    const size_t NEL = (size_t)E_TOT * B;   // 8.39M floats = 32 MB
    float* buf0 = (float*)d_ws;             // x0T (gather source L0 + residual)
    float* buf1 = buf0 + NEL;
    float* buf2 = buf1 + NEL;

    transpose_in_kernel<<<E_TOT / 64, 256, 0, stream>>>(x0, buf0);

    const float* cur = buf0;
    float* nxt = buf1;
    for (int l = 0; l < LAYERS; ++l) {
        if (l == LAYERS - 1) {
            layer_kernel<true><<<GRID, TPB, 0, stream>>>(
                cur, buf0, W1, b1, W2, b2, in_ixs, out);
        } else {
            layer_kernel<false><<<GRID, TPB, 0, stream>>>(
                cur, buf0, W1, b1, W2, b2, in_ixs, nxt);
            cur = nxt;
            nxt = (cur == buf1) ? buf2 : buf1;
        }
    }
}

// Round 6
// 325.848 us; speedup vs baseline: 2.2660x; 1.1952x over previous
//
#include <hip/hip_runtime.h>
#include <math.h>

#define F_NODES 16384
#define DEG 8
#define E_TOT (F_NODES * DEG)   // 131072
#define B 64
#define H 16
#define LAYERS 10
#define NPW 2                   // nodes per wave

typedef unsigned short bf16_t;

__device__ __forceinline__ bf16_t f32_to_bf16(float f)
{
    unsigned u = __float_as_uint(f);
    u = (u + 0x7FFFu + ((u >> 16) & 1u)) >> 16;   // round-to-nearest-even
    return (bf16_t)u;
}
__device__ __forceinline__ float bf16_to_f32(bf16_t h)
{
    return __uint_as_float((unsigned)h << 16);
}

// ---------------------------------------------------------------------------
// Transpose x0 (B, E) -> x0T (E, B) fp32 AND x0T16 (E, B) bf16.
// ---------------------------------------------------------------------------
__global__ __launch_bounds__(256) void transpose_in_kernel(
    const float* __restrict__ x0, float* __restrict__ xT,
    bf16_t* __restrict__ xT16)
{
    __shared__ float tile[64 * 65];
    const int e0 = blockIdx.x * 64;
    const int c  = threadIdx.x & 63;
    const int r  = threadIdx.x >> 6;

    #pragma unroll
    for (int i = 0; i < 16; ++i) {
        const int b = r + i * 4;
        tile[c * 65 + b] = x0[(size_t)b * E_TOT + e0 + c];
    }
    __syncthreads();
    const int b = threadIdx.x & 63;
    #pragma unroll
    for (int i = 0; i < 16; ++i) {
        const int el = r + i * 4;
        const float v = tile[el * 65 + b];
        const size_t idx = (size_t)(e0 + el) * B + b;
        xT[idx]   = v;
        xT16[idx] = f32_to_bf16(v);
    }
}

// inv[P[k]] = k  (P = flat in_ixs, a permutation of E)
__global__ __launch_bounds__(256) void build_inv_kernel(
    const int* __restrict__ in_ixs, int* __restrict__ inv)
{
    const int k = blockIdx.x * 256 + threadIdx.x;
    inv[in_ixs[k]] = k;
}

__device__ __forceinline__ float fast_elu(float x)
{
    float e = __builtin_amdgcn_exp2f(x * 1.44269504088896340736f) - 1.0f;
    return x > 0.0f ? x : e;
}

// ---------------------------------------------------------------------------
// One GSNN layer. Inter-layer activations z are bf16, PRE-PERMUTED
// (z[k] = x[P[k]]): reads sequential, permutation applied via scatter-stores
// through inv. fp32 math throughout; one wave owns NPW=2 nodes, lane = batch.
//   MODE 0: first  — gather fp32 x0T[P[e]], residual fp32 x0T, scatter bf16 z
//   MODE 1: middle — seq bf16 z in, residual bf16 x0T16,      scatter bf16 z
//   MODE 2: final  — seq bf16 z in, residual fp32 x0T,  fp32 (B,E) out
// Weights/biases/indices are wave-uniform -> s_load.
// ---------------------------------------------------------------------------
template <int MODE>
__global__ __launch_bounds__(256) void layer_kernel(
    const bf16_t* __restrict__ zin,    // (E, B) bf16 pre-permuted
    const float*  __restrict__ x0T,    // (E, B) fp32
    const bf16_t* __restrict__ x0T16,  // (E, B) bf16
    const float*  __restrict__ W1,     // (F, H, DEG)
    const float*  __restrict__ b1,     // (F, H)
    const float*  __restrict__ W2,     // (F, DEG, H)
    const float*  __restrict__ b2,     // (F, DEG)
    const int*    __restrict__ in_ixs, // (F, DEG) = P
    const int*    __restrict__ inv,    // (E)      = P^-1
    bf16_t* __restrict__ zout,         // (E, B) bf16 pre-permuted
    float*  __restrict__ out)          // (B, E) fp32 final
{
    const int lane    = threadIdx.x & 63;
    const int wv      = threadIdx.x >> 6;
    const int wave_id = (int)blockIdx.x * 4 + wv;

    #pragma unroll
    for (int n = 0; n < NPW; ++n) {
        const int f = __builtin_amdgcn_readfirstlane(wave_id * NPW + n);

        // ---- inputs + residual, all loads issued up front ----
        float g[DEG], r[DEG];
        if (MODE == 0) {
            const int* ixp = in_ixs + f * DEG;              // s_load
            const float* rp = x0T + (size_t)f * DEG * B + lane;
            #pragma unroll
            for (int d = 0; d < DEG; ++d) {
                g[d] = x0T[(size_t)ixp[d] * B + lane];
                r[d] = rp[d * B];
            }
        } else if (MODE == 1) {
            const bf16_t* zp  = zin   + (size_t)f * DEG * B + lane;
            const bf16_t* rp  = x0T16 + (size_t)f * DEG * B + lane;
            #pragma unroll
            for (int d = 0; d < DEG; ++d) {
                g[d] = bf16_to_f32(zp[d * B]);
                r[d] = bf16_to_f32(rp[d * B]);
            }
        } else {
            const bf16_t* zp = zin + (size_t)f * DEG * B + lane;
            const float*  rp = x0T + (size_t)f * DEG * B + lane;
            #pragma unroll
            for (int d = 0; d < DEG; ++d) {
                g[d] = bf16_to_f32(zp[d * B]);
                r[d] = rp[d * B];
            }
        }

        // ---- h = elu(g @ W1^T + b1) ----
        const float* w1  = W1 + f * (H * DEG);
        const float* bb1 = b1 + f * H;
        float h[H];
        #pragma unroll
        for (int j = 0; j < H; ++j) {
            float acc = bb1[j];
            #pragma unroll
            for (int d = 0; d < DEG; ++d)
                acc = fmaf(w1[j * DEG + d], g[d], acc);
            h[j] = fast_elu(acc);
        }

        // ---- o = h @ W2^T + b2 + residual ----
        const float* w2  = W2 + f * (DEG * H);
        const float* bb2 = b2 + f * DEG;
        float o[DEG];
        #pragma unroll
        for (int d = 0; d < DEG; ++d) {
            float acc = bb2[d];
            #pragma unroll
            for (int j = 0; j < H; ++j)
                acc = fmaf(w2[d * H + j], h[j], acc);
            o[d] = acc + r[d];
        }

        if (MODE == 2) {
            // final: natural (B, E) fp32; lane b owns 8 consecutive floats
            float4 v0 = make_float4(o[0], o[1], o[2], o[3]);
            float4 v1 = make_float4(o[4], o[5], o[6], o[7]);
            float4* dst = (float4*)(out + (size_t)lane * E_TOT + f * DEG);
            dst[0] = v0;
            dst[1] = v1;
        } else {
            // scatter into pre-permuted bf16 layout for next layer's seq read
            const int* invp = inv + f * DEG;                // s_load
            #pragma unroll
            for (int d = 0; d < DEG; ++d)
                zout[(size_t)invp[d] * B + lane] = f32_to_bf16(o[d]);
        }
    }
}

extern "C" void kernel_launch(void* const* d_in, const int* in_sizes, int n_in,
                              void* d_out, int out_size, void* d_ws, size_t ws_size,
                              hipStream_t stream)
{
    const float* x0     = (const float*)d_in[0];
    const float* W1     = (const float*)d_in[1];
    const float* b1     = (const float*)d_in[2];
    const float* W2     = (const float*)d_in[3];
    const float* b2     = (const float*)d_in[4];
    const int*   in_ixs = (const int*)d_in[5];
    float* out = (float*)d_out;

    const size_t NEL = (size_t)E_TOT * B;        // 8.39M elements
    float*  x0T   = (float*)d_ws;                // 32 MB fp32
    bf16_t* x0T16 = (bf16_t*)(x0T + NEL);        // 16 MB bf16
    bf16_t* zA    = x0T16 + NEL;                 // 16 MB bf16
    bf16_t* zB    = zA + NEL;                    // 16 MB bf16
    int*    inv   = (int*)(zB + NEL);            // 512 KB

    transpose_in_kernel<<<E_TOT / 64, 256, 0, stream>>>(x0, x0T, x0T16);
    build_inv_kernel<<<E_TOT / 256, 256, 0, stream>>>(in_ixs, inv);

    const int grid = F_NODES / (4 * NPW);        // 2048 blocks

    // layer 0: gather fp32, scatter bf16 into zA
    layer_kernel<0><<<grid, 256, 0, stream>>>(
        nullptr, x0T, x0T16, W1, b1, W2, b2, in_ixs, inv, zA, nullptr);

    const bf16_t* cur = zA;
    bf16_t* nxt = zB;
    for (int l = 1; l < LAYERS - 1; ++l) {
        layer_kernel<1><<<grid, 256, 0, stream>>>(
            cur, x0T, x0T16, W1, b1, W2, b2, in_ixs, inv, nxt, nullptr);
        cur = nxt;
        nxt = (nxt == zA) ? zB : zA;
    }

    // final layer: fp32 residual + fp32 (B, E) output
    layer_kernel<2><<<grid, 256, 0, stream>>>(
        cur, x0T, x0T16, W1, b1, W2, b2, in_ixs, inv, nullptr, out);
}

// Round 7
// 295.000 us; speedup vs baseline: 2.5029x; 1.1046x over previous
//
#include <hip/hip_runtime.h>
#include <math.h>

#define F_NODES 16384
#define DEG 8
#define E_TOT (F_NODES * DEG)   // 131072
#define B 64
#define H 16
#define LAYERS 10
#define NPW 2                   // nodes per wave

typedef unsigned short bf16_t;

__device__ __forceinline__ bf16_t f32_to_bf16(float f)
{
    unsigned u = __float_as_uint(f);
    u = (u + 0x7FFFu + ((u >> 16) & 1u)) >> 16;   // round-to-nearest-even
    return (bf16_t)u;
}
__device__ __forceinline__ float bf16_to_f32(bf16_t h)
{
    return __uint_as_float((unsigned)h << 16);
}
// packed-pair unpack: elem0 = bits[15:0], elem1 = bits[31:16]
__device__ __forceinline__ float bfu_lo(unsigned u) { return __uint_as_float(u << 16); }
__device__ __forceinline__ float bfu_hi(unsigned u) { return __uint_as_float(u & 0xFFFF0000u); }

// ---------------------------------------------------------------------------
// Transpose x0 (B, E) fp32 -> x0T16 (E, B) bf16 (only copy of the residual).
// ---------------------------------------------------------------------------
__global__ __launch_bounds__(256) void transpose_in_kernel(
    const float* __restrict__ x0, bf16_t* __restrict__ xT16)
{
    __shared__ float tile[64 * 65];
    const int e0 = blockIdx.x * 64;
    const int c  = threadIdx.x & 63;
    const int r  = threadIdx.x >> 6;

    #pragma unroll
    for (int i = 0; i < 16; ++i) {
        const int b = r + i * 4;
        tile[c * 65 + b] = x0[(size_t)b * E_TOT + e0 + c];
    }
    __syncthreads();
    const int b = threadIdx.x & 63;
    #pragma unroll
    for (int i = 0; i < 16; ++i) {
        const int el = r + i * 4;
        xT16[(size_t)(e0 + el) * B + b] = f32_to_bf16(tile[el * 65 + b]);
    }
}

// inv[P[k]] = k  (P = flat in_ixs, a permutation of E)
__global__ __launch_bounds__(256) void build_inv_kernel(
    const int* __restrict__ in_ixs, int* __restrict__ inv)
{
    const int k = blockIdx.x * 256 + threadIdx.x;
    inv[in_ixs[k]] = k;
}

// Pack W1/W2 fp32 -> bf16 pairs (one dword = 2 consecutive weights).
// F*H*DEG/2 = 1,048,576 pairs each.
__global__ __launch_bounds__(256) void pack_weights_kernel(
    const float* __restrict__ W1, const float* __restrict__ W2,
    unsigned* __restrict__ W1b, unsigned* __restrict__ W2b)
{
    const int i = blockIdx.x * 256 + threadIdx.x;
    float2 a = ((const float2*)W1)[i];
    W1b[i] = (unsigned)f32_to_bf16(a.x) | ((unsigned)f32_to_bf16(a.y) << 16);
    float2 c = ((const float2*)W2)[i];
    W2b[i] = (unsigned)f32_to_bf16(c.x) | ((unsigned)f32_to_bf16(c.y) << 16);
}

__device__ __forceinline__ float fast_elu(float x)
{
    float e = __builtin_amdgcn_exp2f(x * 1.44269504088896340736f) - 1.0f;
    return x > 0.0f ? x : e;
}

// ---------------------------------------------------------------------------
// One GSNN layer, all streams bf16 (fp32 accumulation). z is PRE-PERMUTED
// (z[k] = x[P[k]]): seq reads; permutation applied by scatter-stores via inv.
//   MODE 0: first  — gather bf16 x0T16[P[e]],           scatter bf16 z
//   MODE 1: middle — seq bf16 z in,                     scatter bf16 z
//   MODE 2: final  — seq bf16 z in,            fp32 (B,E) natural out
// Residual always read seq from bf16 x0T16. Weights bf16-packed (uniform
// s_load dwords; unpack = 16-bit shift). Biases fp32.
// ---------------------------------------------------------------------------
template <int MODE>
__global__ __launch_bounds__(256) void layer_kernel(
    const bf16_t*  __restrict__ zin,    // (E, B) bf16 pre-permuted
    const bf16_t*  __restrict__ x0T16,  // (E, B) bf16
    const unsigned* __restrict__ W1b,   // (F, H, DEG/2) packed
    const float*   __restrict__ b1,     // (F, H)
    const unsigned* __restrict__ W2b,   // (F, DEG, H/2) packed
    const float*   __restrict__ b2,     // (F, DEG)
    const int*     __restrict__ in_ixs, // (F, DEG) = P
    const int*     __restrict__ inv,    // (E)      = P^-1
    bf16_t* __restrict__ zout,          // (E, B) bf16 pre-permuted
    float*  __restrict__ out)           // (B, E) fp32 final
{
    const int lane    = threadIdx.x & 63;
    const int wv      = threadIdx.x >> 6;
    const int wave_id = (int)blockIdx.x * 4 + wv;

    #pragma unroll
    for (int n = 0; n < NPW; ++n) {
        const int f = __builtin_amdgcn_readfirstlane(wave_id * NPW + n);

        // ---- inputs + residual, all loads issued up front ----
        float g[DEG], r[DEG];
        {
            const bf16_t* rp = x0T16 + (size_t)f * DEG * B + lane;
            if (MODE == 0) {
                const int* ixp = in_ixs + f * DEG;          // s_load
                #pragma unroll
                for (int d = 0; d < DEG; ++d) {
                    g[d] = bf16_to_f32(x0T16[(size_t)ixp[d] * B + lane]);
                    r[d] = bf16_to_f32(rp[d * B]);
                }
            } else {
                const bf16_t* zp = zin + (size_t)f * DEG * B + lane;
                #pragma unroll
                for (int d = 0; d < DEG; ++d) {
                    g[d] = bf16_to_f32(zp[d * B]);
                    r[d] = bf16_to_f32(rp[d * B]);
                }
            }
        }

        // ---- h = elu(g @ W1^T + b1) ----
        const unsigned* w1 = W1b + f * (H * DEG / 2);       // 64 dwords
        const float*   bb1 = b1 + f * H;
        float h[H];
        #pragma unroll
        for (int j = 0; j < H; ++j) {
            float acc = bb1[j];
            #pragma unroll
            for (int dp = 0; dp < DEG / 2; ++dp) {
                const unsigned u = w1[j * (DEG / 2) + dp];
                acc = fmaf(bfu_lo(u), g[2 * dp],     acc);
                acc = fmaf(bfu_hi(u), g[2 * dp + 1], acc);
            }
            h[j] = fast_elu(acc);
        }

        // ---- o = h @ W2^T + b2 + residual ----
        const unsigned* w2 = W2b + f * (DEG * H / 2);       // 64 dwords
        const float*   bb2 = b2 + f * DEG;
        float o[DEG];
        #pragma unroll
        for (int d = 0; d < DEG; ++d) {
            float acc = bb2[d];
            #pragma unroll
            for (int jp = 0; jp < H / 2; ++jp) {
                const unsigned u = w2[d * (H / 2) + jp];
                acc = fmaf(bfu_lo(u), h[2 * jp],     acc);
                acc = fmaf(bfu_hi(u), h[2 * jp + 1], acc);
            }
            o[d] = acc + r[d];
        }

        if (MODE == 2) {
            // final: natural (B, E) fp32; lane b owns 8 consecutive floats
            float4 v0 = make_float4(o[0], o[1], o[2], o[3]);
            float4 v1 = make_float4(o[4], o[5], o[6], o[7]);
            float4* dst = (float4*)(out + (size_t)lane * E_TOT + f * DEG);
            dst[0] = v0;
            dst[1] = v1;
        } else {
            // scatter into pre-permuted bf16 layout for next layer's seq read
            const int* invp = inv + f * DEG;                // s_load
            #pragma unroll
            for (int d = 0; d < DEG; ++d)
                zout[(size_t)invp[d] * B + lane] = f32_to_bf16(o[d]);
        }
    }
}

extern "C" void kernel_launch(void* const* d_in, const int* in_sizes, int n_in,
                              void* d_out, int out_size, void* d_ws, size_t ws_size,
                              hipStream_t stream)
{
    const float* x0     = (const float*)d_in[0];
    const float* W1     = (const float*)d_in[1];
    const float* b1     = (const float*)d_in[2];
    const float* W2     = (const float*)d_in[3];
    const float* b2     = (const float*)d_in[4];
    const int*   in_ixs = (const int*)d_in[5];
    float* out = (float*)d_out;

    const size_t NEL = (size_t)E_TOT * B;        // 8.39M elements
    bf16_t*   x0T16 = (bf16_t*)d_ws;             // 16 MB
    bf16_t*   zA    = x0T16 + NEL;               // 16 MB
    bf16_t*   zB    = zA + NEL;                  // 16 MB
    int*      inv   = (int*)(zB + NEL);          // 512 KB
    unsigned* W1b   = (unsigned*)(inv + E_TOT);  // 4.2 MB
    unsigned* W2b   = W1b + F_NODES * H * DEG / 2;

    transpose_in_kernel<<<E_TOT / 64, 256, 0, stream>>>(x0, x0T16);
    build_inv_kernel<<<E_TOT / 256, 256, 0, stream>>>(in_ixs, inv);
    pack_weights_kernel<<<F_NODES * H * DEG / 2 / 256, 256, 0, stream>>>(
        W1, W2, W1b, W2b);

    const int grid = F_NODES / (4 * NPW);        // 2048 blocks

    layer_kernel<0><<<grid, 256, 0, stream>>>(
        nullptr, x0T16, W1b, b1, W2b, b2, in_ixs, inv, zA, nullptr);

    const bf16_t* cur = zA;
    bf16_t* nxt = zB;
    for (int l = 1; l < LAYERS - 1; ++l) {
        layer_kernel<1><<<grid, 256, 0, stream>>>(
            cur, x0T16, W1b, b1, W2b, b2, in_ixs, inv, nxt, nullptr);
        cur = nxt;
        nxt = (nxt == zA) ? zB : zA;
    }

    layer_kernel<2><<<grid, 256, 0, stream>>>(
        cur, x0T16, W1b, b1, W2b, b2, in_ixs, inv, nullptr, out);
}